// Round 7
// baseline (275.340 us; speedup 1.0000x reference)
//
#include <hip/hip_runtime.h>
#include <cstdint>
#include <cmath>

#define Bn 4096
#define Dn 256
#define On 256

typedef __bf16 v8bf __attribute__((ext_vector_type(8)));
typedef float  v16f __attribute__((ext_vector_type(16)));
typedef unsigned short us8 __attribute__((ext_vector_type(8)));

__device__ __forceinline__ unsigned short f2bf(float f) {
    // round-to-nearest-even fp32 -> bf16 (inputs are finite normals)
    unsigned int u = __builtin_bit_cast(unsigned int, f);
    unsigned int r = (u + 0x7fffu + ((u >> 16) & 1u)) >> 16;
    return (unsigned short)r;
}

__device__ __forceinline__ void gl_lds16(const void* g, void* l) {
    __builtin_amdgcn_global_load_lds(
        (const __attribute__((address_space(1))) void*)(uintptr_t)g,
        (__attribute__((address_space(3))) void*)(uintptr_t)l, 16, 0, 0);
}

// ---------------------------------------------------------------------------
// Kernel 1: FUSED prep. Blocks [0,2560): build A' = 32x32x16 MFMA A-operand
// order of (triu(rots,1)+triu^T+diag(scales)), bf16:
//   A'[(o*8+s)*16+t][lane][j] = A[o][i = s*32+(lane&31)][k = t*16+(lane>>5)*8+j]
// 1KB per (o, 32-i-strip s, 16-k-step t); fuzzy_main loads an A-frag as ONE
// coalesced global_load_dwordx4 at base+lane*16. One block per unordered
// 64x64 tile pair (10/o, mirror read once). Blocks [2560,2816): x -> bf16.
// ---------------------------------------------------------------------------
__global__ __launch_bounds__(256) void prep(
    const float* __restrict__ scales, const float* __restrict__ rots,
    const float* __restrict__ x, unsigned short* __restrict__ Ap,
    unsigned short* __restrict__ xb) {
    const int bid = blockIdx.x;
    const int tid = threadIdx.x;

    if (bid >= 2560) {                   // ---- cvt_x part: 256 blocks ----
        const int cb = bid - 2560;
#pragma unroll
        for (int s = 0; s < 4; ++s) {
            const int i = cb * 4096 + s * 1024 + tid * 4;
            const float4 v = *(const float4*)(x + i);
            ushort4 u;
            u.x = f2bf(v.x); u.y = f2bf(v.y); u.z = f2bf(v.z); u.w = f2bf(v.w);
            *(ushort4*)(xb + i) = u;
        }
        return;
    }

    // ---- build_A' part: 2560 blocks, one per unordered 64x64 tile pair ----
    static const int TI[10] = {0, 0, 0, 0, 1, 1, 1, 2, 2, 3};
    static const int TJ[10] = {0, 1, 2, 3, 1, 2, 3, 2, 3, 3};
    const int o  = bid / 10;
    const int p  = bid - o * 10;
    const int ti = TI[p], tj = TJ[p];

    __shared__ float t[64][68];          // 68: 16B-aligned rows, padded banks
    const float* src = rots + (size_t)o * Dn * Dn + (size_t)(ti * 64) * Dn + tj * 64;
#pragma unroll
    for (int s = 0; s < 4; ++s) {
        const int idx = s * 256 + tid;
        const int r = idx >> 4, c = (idx & 15) * 4;
        const float4 v = *(const float4*)(src + r * Dn + c);
        *(float4*)&t[r][c] = v;
    }
    __syncthreads();

    const int L   = tid & 63;
    const int kl  = (tid >> 6) & 3;      // local 16-k-step, 0..3
    const int i32 = L & 31;
    const int kb  = kl * 16 + (L >> 5) * 8;   // local k base, 0..56

    // phase U: output strips of row-tile ti, ksteps of col-tile tj
#pragma unroll
    for (int it = 0; it < 2; ++it) {
        const int r = it * 32 + i32;     // local row (= i within tile)
        float v[8];
        if (ti == tj) {
#pragma unroll
            for (int q = 0; q < 8; ++q) {
                const int cc = kb + q;
                v[q] = (r < cc) ? t[r][cc]
                     : ((r > cc) ? t[cc][r] : scales[o * Dn + ti * 64 + r]);
            }
        } else {
            const float4 a = *(const float4*)&t[r][kb];
            const float4 b = *(const float4*)&t[r][kb + 4];
            v[0] = a.x; v[1] = a.y; v[2] = a.z; v[3] = a.w;
            v[4] = b.x; v[5] = b.y; v[6] = b.z; v[7] = b.w;
        }
        us8 u;
#pragma unroll
        for (int q = 0; q < 8; ++q) u[q] = f2bf(v[q]);
        const size_t off = ((size_t)((o * 8 + ti * 2 + it) * 16 + tj * 4 + kl)) * 512 + L * 8;
        *(us8*)(Ap + off) = u;           // 64 consecutive L -> 1KB coalesced
    }

    if (ti != tj) {                      // phase L: mirror tile (tj,ti), transposed
#pragma unroll
        for (int it = 0; it < 2; ++it) {
            const int r = it * 32 + i32; // local row of the OUTPUT (mirror) tile
            us8 u;
#pragma unroll
            for (int q = 0; q < 8; ++q) u[q] = f2bf(t[kb + q][r]);
            const size_t off = ((size_t)((o * 8 + tj * 2 + it) * 16 + ti * 4 + kl)) * 512 + L * 8;
            *(us8*)(Ap + off) = u;
        }
    }
}

// ---------------------------------------------------------------------------
// Kernel 2: fused GEMM (y = A[o] x + c) + squared-norm + bell membership.
// 32x32x16 MFMA (ceiling 2382 TF; operand + C/D maps validated by round 3's
// passing run). Xs staged ONCE in B-FRAGMENT ORDER: chunk (t*4+nb) holds
// B[k=t*16+(lane>>5)*8+j][n=nb*32+(lane&31)] at base+lane*16 — every
// ds_read_b128 is lane-linear => conflict-free BY CONSTRUCTION (all 4 waves
// share B-frags; the global side of global_load_lds is a free per-lane
// gather). Barrier-free K-loop, FULL ping-pong on both operands: per kstep
// issue 2 global A-frag loads + 4 ds_reads for t+1, then 8 MFMAs on t (the
// ~270-cyc burst hides both latencies). Regs: 128 AGPR acc + ~110 VGPR < 256
// => 2 waves/SIMD preserved. Grid 8192, round-4 proven XCD decode (~2 live
// o/XCD -> A' L2-resident, 24.8 MB FETCH).
// ---------------------------------------------------------------------------
__global__ __launch_bounds__(256, 2) void fuzzy_main(
    const unsigned short* __restrict__ Ap, const unsigned short* __restrict__ xb,
    const float* __restrict__ cent, const float* __restrict__ bvals,
    float* __restrict__ obase, int sb, int so) {
    __shared__ __align__(16) unsigned short Xs[64 * 512];   // 64 KB, chunk=1KB
    __shared__ float ssbuf[4][128];
    __shared__ float centL[Dn];

    const int tid  = threadIdx.x;
    const int lane = tid & 63;
    const int wv   = tid >> 6;
    const int Lb = blockIdx.x;
    const int o  = (Lb & 7) * 32 + (Lb >> 8);
    const int b0 = ((Lb >> 3) & 31) * 128;

    centL[tid] = cent[o * Dn + tid];

    // stage Xs once, B-frag order: 64 chunks, 16 per wave.
    // dest = chunk*1024B + lane*16B (wave-uniform + lane*16) ✓
#pragma unroll
    for (int q = 0; q < 16; ++q) {
        const int R  = wv * 16 + q;
        const int tt = R >> 2, nb = R & 3;
        gl_lds16(xb + (size_t)(b0 + nb * 32 + (lane & 31)) * Dn + tt * 16 + (lane >> 5) * 8,
                 &Xs[R * 512 + lane * 8]);
    }

    const unsigned short* Aw = Ap + (size_t)(o * 8 + wv * 2) * 16 * 512;
    // A-frag(mi, t) = Aw + (mi*16 + t)*512 + lane*8   (1KB, lane-linear)

    v16f acc[2][4];
#pragma unroll
    for (int mi = 0; mi < 2; ++mi)
#pragma unroll
        for (int nb = 0; nb < 4; ++nb)
#pragma unroll
            for (int rg = 0; rg < 16; ++rg)
                acc[mi][nb][rg] = 0.f;

    v8bf af[2][2], xf[2][4];
#pragma unroll
    for (int mi = 0; mi < 2; ++mi)       // t=0 A-frags: global, no barrier dep
        af[0][mi] = *(const v8bf*)(Aw + (size_t)(mi * 16) * 512 + lane * 8);

    __syncthreads();   // the ONLY barrier before the epilogue

#pragma unroll
    for (int nb = 0; nb < 4; ++nb)       // t=0 B-frags
        xf[0][nb] = *(const v8bf*)&Xs[nb * 512 + lane * 8];

#pragma unroll
    for (int t = 0; t < 16; ++t) {
        const int cur = t & 1, nxt = cur ^ 1;
        if (t < 15) {
#pragma unroll
            for (int mi = 0; mi < 2; ++mi)
                af[nxt][mi] = *(const v8bf*)(Aw + (size_t)(mi * 16 + t + 1) * 512 + lane * 8);
#pragma unroll
            for (int nb = 0; nb < 4; ++nb)
                xf[nxt][nb] = *(const v8bf*)&Xs[((t + 1) * 4 + nb) * 512 + lane * 8];
        }
#pragma unroll
        for (int mi = 0; mi < 2; ++mi)
#pragma unroll
            for (int nb = 0; nb < 4; ++nb)
                acc[mi][nb] = __builtin_amdgcn_mfma_f32_32x32x16_bf16(
                    af[cur][mi], xf[cur][nb], acc[mi][nb], 0, 0, 0);
    }

    // epilogue: y = acc + centroid; sum_i y^2. C/D map (validated r3):
    // col = lane&31 = b, row(i) = (rg&3) + 8*(rg>>2) + 4*(lane>>5).
    const int half = lane >> 5;
#pragma unroll
    for (int nb = 0; nb < 4; ++nb) {
        float v = 0.f;
#pragma unroll
        for (int mi = 0; mi < 2; ++mi)
#pragma unroll
            for (int rg = 0; rg < 16; ++rg) {
                const int io = (rg & 3) + 8 * (rg >> 2) + 4 * half;
                const float y = acc[mi][nb][rg] + centL[wv * 64 + mi * 32 + io];
                v += y * y;
            }
        v += __shfl_xor(v, 32);          // merge the two k-halves (same b col)
        if (lane < 32) ssbuf[wv][nb * 32 + lane] = v;
    }
    __syncthreads();
    if (tid < 128) {
        const float ssq = ssbuf[0][tid] + ssbuf[1][tid] + ssbuf[2][tid] + ssbuf[3][tid];
        obase[(size_t)(b0 + tid) * sb + (size_t)o * so] =
            1.0f / (1.0f + powf(ssq, bvals[o]));
    }
}

// ---------------------------------------------------------------------------
// Kernel 3: transpose outT [O][B] -> out [B][O] (both coalesced, 64x64 tiles)
// ---------------------------------------------------------------------------
__global__ __launch_bounds__(256) void transp(const float* __restrict__ outT,
                                              float* __restrict__ out) {
    __shared__ float t[64][65];
    const int bb = blockIdx.x * 64;
    const int ob = blockIdx.y * 64;
    const int tid = threadIdx.x;
    const int r = tid >> 4;
    const int c = (tid & 15) * 4;
#pragma unroll
    for (int s = 0; s < 4; ++s) {
        const int rr = s * 16 + r;
        const float4 v = *(const float4*)(outT + (size_t)(ob + rr) * Bn + bb + c);
        t[rr][c] = v.x; t[rr][c + 1] = v.y; t[rr][c + 2] = v.z; t[rr][c + 3] = v.w;
    }
    __syncthreads();
#pragma unroll
    for (int s = 0; s < 4; ++s) {
        const int rr = s * 16 + r;
        float4 w;
        w.x = t[c][rr]; w.y = t[c + 1][rr]; w.z = t[c + 2][rr]; w.w = t[c + 3][rr];
        *(float4*)(out + (size_t)(bb + rr) * On + ob + c) = w;
    }
}

// ---------------------------------------------------------------------------
// Fallback (only if d_ws is too small): exact fp32, slow but correct.
// ---------------------------------------------------------------------------
__global__ void fallback_kernel(const float* __restrict__ x, const float* __restrict__ scales,
                                const float* __restrict__ rots, const float* __restrict__ cent,
                                const float* __restrict__ bvals, float* __restrict__ out) {
    const int b = blockIdx.x * blockDim.x + threadIdx.x;
    const int o = blockIdx.y;
    if (b >= Bn) return;
    const float* R  = rots + (size_t)o * Dn * Dn;
    const float* xv = x + (size_t)b * Dn;
    float ss = 0.f;
    for (int i = 0; i < Dn; ++i) {
        float a = cent[o * Dn + i];
        for (int j = 0; j < Dn; ++j) {
            const float w = (j > i) ? R[i * Dn + j]
                          : ((j < i) ? R[j * Dn + i] : scales[o * Dn + i]);
            a += w * xv[j];
        }
        ss += a * a;
    }
    out[(size_t)b * On + o] = 1.f / (1.f + powf(ss, bvals[o]));
}

extern "C" void kernel_launch(void* const* d_in, const int* in_sizes, int n_in,
                              void* d_out, int out_size, void* d_ws, size_t ws_size,
                              hipStream_t stream) {
    const float* x         = (const float*)d_in[0];
    const float* scales    = (const float*)d_in[1];
    const float* rots      = (const float*)d_in[2];
    const float* centroids = (const float*)d_in[3];
    const float* bvals     = (const float*)d_in[4];
    float* out = (float*)d_out;

    const size_t needA = (size_t)On * Dn * Dn * sizeof(unsigned short); // 33.5 MB
    const size_t needX = (size_t)Bn * Dn * sizeof(unsigned short);      //  2.1 MB
    const size_t needT = (size_t)On * Bn * sizeof(float);               //  4.2 MB

    if (ws_size >= needA + needX) {
        unsigned short* Ap = (unsigned short*)d_ws;
        unsigned short* xb = (unsigned short*)((char*)d_ws + needA);
        prep<<<dim3(2816), 256, 0, stream>>>(scales, rots, x, Ap, xb);
        if (ws_size >= needA + needX + needT) {
            float* outT = (float*)((char*)d_ws + needA + needX);
            fuzzy_main<<<dim3(8192), 256, 0, stream>>>(Ap, xb, centroids, bvals,
                                                       outT, 1, Bn);
            transp<<<dim3(Bn / 64, On / 64), 256, 0, stream>>>(outT, out);
        } else {
            fuzzy_main<<<dim3(8192), 256, 0, stream>>>(Ap, xb, centroids, bvals,
                                                       out, On, 1);
        }
    } else {
        fallback_kernel<<<dim3(Bn / 256, On), 256, 0, stream>>>(x, scales, rots, centroids,
                                                                bvals, out);
    }
}